// Round 10
// baseline (78.086 us; speedup 1.0000x reference)
//
#include <hip/hip_runtime.h>

// out[co*4+n, ci*4+o, y, x] = sum_{c,ky,kx} k1[co*4+n, ci*4+c, y+ky-7, x+kx-7]
//                                         * k2[co*4+o, ci*4+c, ky, kx]
// MFMA per (co,ci,c,ky):  OUT[y][x] (o=0..3) += sum_u Apad[y+ky][u] * k2[o][ky][u-x]
//   A-frag: lane(y=l&15, kg=l>>4) reads 8 contiguous bf16 (ds_read_b128, imm offs)
//   B-frag: DIRECT ds_read_b32 (imm offs) from pre-swizzled PAIR tables:
//     tbl01[c][ky][slot] (u64) = {o0[s-15],o0[s-14],o1[s-15],o1[s-14]} (0 outside)
//     word t of o0-frag = dword 2*(base+2t)+0, o1-frag = +1 (base = kg*8-x+15).
//     Zero perms / zero repack VALU in the K-loop; DS-merge pairs the b32s into
//     ds_read2_b32 with consecutive dests. Row stride 33 units: max touched slot
//     46 < 33+14 (next row's first nonzero) -> pair bleed lands on true zeros.
// 8 waves (512 thr), wave = (c = wid&3, np = wid>>2 handling n in {2np,2np+1}).
// acc[2][4] = 32 regs. Arena 20496 (Apad) + 32768 (2 pair tables) = 53264 B
// -> 3 blocks/CU (24 waves = 75% cap; regs ~70 -> 7 w/SIMD, not binding).
// Apad 2-D shared-pad tiling: 8 vertical bands (stride 22 rows) x 2 horizontal
//   (cols 0/24); only the discarded yl=15 output row ever reads neighbor data.

typedef float f32x4 __attribute__((ext_vector_type(4)));
typedef __bf16 bf16x8 __attribute__((ext_vector_type(8)));

#define KS 15
#define SP 225
#define NCH 256
#define RSTRIDE 56                    // shorts per Apad row
#define ROWS 183                      // 22*7 + 29
#define APAD_SHORTS (ROWS * RSTRIDE)  // 10248 shorts = 20496 B
#define TBL_OFF (APAD_SHORTS * 2)     // 20496 B, 16B aligned
#define TBL_UPC 512                   // u64 units per (c) per table (15*33+47=509)
#define TBL_BYTES (4 * TBL_UPC * 8)   // 16384 B per table
#define ARENA_B (TBL_OFF + 2 * TBL_BYTES)   // 53264 B

__device__ __forceinline__ unsigned short f2bf(float f) {
    unsigned u = __builtin_bit_cast(unsigned, f);
    u += 0x7FFFu + ((u >> 16) & 1u);   // RNE (finite normals)
    return (unsigned short)(u >> 16);
}

__global__ __launch_bounds__(512, 6)
void blade_conv_mfma(const float* __restrict__ k1,
                     const float* __restrict__ k2,
                     float* __restrict__ out) {
    __shared__ __align__(16) unsigned char arena[ARENA_B];
    unsigned short*     Apad  = (unsigned short*)arena;
    unsigned long long* tbl01 = (unsigned long long*)(arena + TBL_OFF);
    unsigned long long* tbl23 = tbl01 + 4 * TBL_UPC;
    float*              slabs = (float*)arena;   // epilogue overlay (20480 B)

    const int tid  = threadIdx.x;
    const int lane = tid & 63;
    const int wid  = tid >> 6;            // 8 waves
    const int c_w  = wid & 3;             // input channel c
    const int np   = wid >> 2;            // n-half: n in {2np, 2np+1}
    const int co = blockIdx.x, ci = blockIdx.y;

    // ---- zero whole arena (53264/16 = 3329 f32x4) ----
    f32x4 z = {0.f, 0.f, 0.f, 0.f};
    for (int i = tid; i < ARENA_B / 16; i += 512) ((f32x4*)arena)[i] = z;
    __syncthreads();

    // ---- stage k1 -> Apad: thread (lo<225, half) owns one (y,x) cell ----
    {
        const int lo = tid & 255, half = tid >> 8;
        if (lo < 225) {
            const int y = lo / 15, x = lo - y * 15;
            #pragma unroll
            for (int j = 0; j < 8; ++j) {
                int n = 2 * half + (j >> 2), cc = j & 3;
                float v = k1[((size_t)((co * 4 + n) * NCH + ci * 4 + cc)) * SP + lo];
                int band = n * 2 + (cc >> 1), side = cc & 1;
                Apad[(band * 22 + 7 + y) * RSTRIDE + side * 24 + 7 + x] = f2bf(v);
            }
        }
    }

    // ---- stage k2 -> pair tables: 960 slots = (4c x 15ky x 16si) ----
    for (int idx = tid; idx < 960; idx += 512) {
        int cc  = idx / 240;
        int rem = idx - cc * 240;
        int ky  = rem >> 4, si = rem & 15;     // slot = 14+si; pair (w[si-1], w[si])
        size_t b0 = ((size_t)(co * 4) * NCH + ci * 4 + cc) * SP + ky * KS;  // o=0
        float e0[4], e1[4];
        #pragma unroll
        for (int o = 0; o < 4; ++o) {
            size_t bo = b0 + (size_t)o * NCH * SP;
            e0[o] = (si >= 1)  ? k2[bo + si - 1] : 0.f;
            e1[o] = (si <= 14) ? k2[bo + si]     : 0.f;
        }
        unsigned l01 = (unsigned)f2bf(e0[0]) | ((unsigned)f2bf(e1[0]) << 16);
        unsigned h01 = (unsigned)f2bf(e0[1]) | ((unsigned)f2bf(e1[1]) << 16);
        unsigned l23 = (unsigned)f2bf(e0[2]) | ((unsigned)f2bf(e1[2]) << 16);
        unsigned h23 = (unsigned)f2bf(e0[3]) | ((unsigned)f2bf(e1[3]) << 16);
        int u = cc * TBL_UPC + 33 * ky + 14 + si;
        tbl01[u] = (unsigned long long)l01 | ((unsigned long long)h01 << 32);
        tbl23[u] = (unsigned long long)l23 | ((unsigned long long)h23 << 32);
    }
    __syncthreads();

    // ---- K loop: 15 ky chunks, K=32 (u) each ----
    f32x4 acc[2][4];
    #pragma unroll
    for (int g = 0; g < 2; ++g)
        #pragma unroll
        for (int o = 0; o < 4; ++o)
            acc[g][o] = z;

    const int yl    = lane & 15;       // output y (M); consuming x for B
    const int kg    = lane >> 4;       // k-group
    const int side_w = c_w & 1, whalf = c_w >> 1;
    const int acol  = side_w * 24 + (kg << 3);
    const int ubase = (kg << 3) - yl + 15;            // unit base within a ky row
    const unsigned* tb01 = (const unsigned*)(tbl01 + c_w * TBL_UPC + ubase);
    const unsigned* tb23 = (const unsigned*)(tbl23 + c_w * TBL_UPC + ubase);
    const unsigned short* ab0 =
        &Apad[(((2 * np + 0) * 2 + whalf) * 22 + yl) * RSTRIDE + acol];
    const unsigned short* ab1 =
        &Apad[(((2 * np + 1) * 2 + whalf) * 22 + yl) * RSTRIDE + acol];

    #pragma unroll
    for (int ky = 0; ky < 15; ++ky) {
        bf16x8 af0 = *(const bf16x8*)(ab0 + ky * RSTRIDE);
        bf16x8 af1 = *(const bf16x8*)(ab1 + ky * RSTRIDE);

        union { bf16x8 v; unsigned u[4]; } bo0, bo1, bo2, bo3;
        #pragma unroll
        for (int t = 0; t < 4; ++t) {
            bo0.u[t] = tb01[66 * ky + 4 * t];
            bo1.u[t] = tb01[66 * ky + 4 * t + 1];
            bo2.u[t] = tb23[66 * ky + 4 * t];
            bo3.u[t] = tb23[66 * ky + 4 * t + 1];
        }
        acc[0][0] = __builtin_amdgcn_mfma_f32_16x16x32_bf16(af0, bo0.v, acc[0][0], 0, 0, 0);
        acc[0][1] = __builtin_amdgcn_mfma_f32_16x16x32_bf16(af0, bo1.v, acc[0][1], 0, 0, 0);
        acc[0][2] = __builtin_amdgcn_mfma_f32_16x16x32_bf16(af0, bo2.v, acc[0][2], 0, 0, 0);
        acc[0][3] = __builtin_amdgcn_mfma_f32_16x16x32_bf16(af0, bo3.v, acc[0][3], 0, 0, 0);
        acc[1][0] = __builtin_amdgcn_mfma_f32_16x16x32_bf16(af1, bo0.v, acc[1][0], 0, 0, 0);
        acc[1][1] = __builtin_amdgcn_mfma_f32_16x16x32_bf16(af1, bo1.v, acc[1][1], 0, 0, 0);
        acc[1][2] = __builtin_amdgcn_mfma_f32_16x16x32_bf16(af1, bo2.v, acc[1][2], 0, 0, 0);
        acc[1][3] = __builtin_amdgcn_mfma_f32_16x16x32_bf16(af1, bo3.v, acc[1][3], 0, 0, 0);
    }

    // ---- cross-wave (c) reduction: 4 rounds (g = r>>1, o-pair = r&1) ----
    const int xl = lane & 15;
    #pragma unroll
    for (int r = 0; r < 4; ++r) {
        const int g = r >> 1, op = r & 1;
        __syncthreads();   // r=0: Apad/tbl reads done; r>0: prev readout done
        {
            float* slab = slabs + wid * 640;   // [2 oi][16 x][20 y]
            #pragma unroll
            for (int oi = 0; oi < 2; ++oi)
                *(f32x4*)&slab[(oi * 16 + xl) * 20 + (kg << 2)] = acc[g][2 * op + oi];
        }
        __syncthreads();
        for (int idx = tid; idx < 900; idx += 512) {
            int q4 = idx / 225;                 // 0..3 = (np_g, oi)
            int rem = idx - q4 * 225;
            int np_g = q4 >> 1, oi = q4 & 1;
            int yy = rem / 15, xx = rem - yy * 15;
            int soff = (oi * 16 + xx) * 20 + yy;
            const float* sb = slabs + np_g * 2560;
            float s = sb[soff] + sb[640 + soff] + sb[1280 + soff] + sb[1920 + soff];
            int n = 2 * np_g + g, o = 2 * op + oi;
            out[((size_t)((co * 4 + n) * NCH + ci * 4 + o)) * SP + rem] = s;
        }
    }
}

extern "C" void kernel_launch(void* const* d_in, const int* in_sizes, int n_in,
                              void* d_out, int out_size, void* d_ws, size_t ws_size,
                              hipStream_t stream) {
    (void)in_sizes; (void)n_in; (void)d_ws; (void)ws_size; (void)out_size;
    const float* k1 = (const float*)d_in[0];
    const float* k2 = (const float*)d_in[1];
    float* out = (float*)d_out;

    dim3 grid(64, 64, 1);
    dim3 block(512, 1, 1);
    hipLaunchKernelGGL(blade_conv_mfma, grid, block, 0, stream, k1, k2, out);
}